// Round 7
// baseline (206.337 us; speedup 1.0000x reference)
//
#include <hip/hip_runtime.h>
#include <hip/hip_bf16.h>
#include <hip/hip_fp16.h>
#include <math.h>

#define N_NODES 100000
#define N_EDGES 1600000
#define IN_F    128
#define NH      8
#define HD      8
#define HID     64   // NH*HD
#define NEG_SLOPE 0.2f

#define BSH   5      // bucket shift: 32 dst nodes per bucket
#define BSZ   32
#define NBK   3125   // 100000/32 exact
#define BCAPG 704    // fixed packed-array stride per bucket (mean 512, +8.5 sigma)
#define BCAP  832    // LDS edge cap in p2agg
#define NBPJ  782    // proj blocks: ceil(100000/128), 128 nodes/block
#define NPB   400    // partition blocks (tail parallelism: 3200 waves)
#define EPB   4000   // edges per partition block (400*4000 = 1.6M exact)
#define GSTR  16     // gcnt stride: one 64B line per bucket (atomic contention)

typedef short bf16x8 __attribute__((ext_vector_type(8)));
typedef float f32x4  __attribute__((ext_vector_type(4)));

static __device__ __forceinline__ unsigned short f2bf(float x) {
    __hip_bfloat16 h = __float2bfloat16(x);
    return *(unsigned short*)&h;
}

// ---------------------------------------------------------------------------
// K0 prep: zero gcnt (padded) + build the 20 KB frag-order B-image once.
// ---------------------------------------------------------------------------
__global__ __launch_bounds__(256) void prep_kernel(
    const float* __restrict__ W, const float* __restrict__ a_src,
    const float* __restrict__ a_dst, unsigned short* __restrict__ Bg,
    int* __restrict__ gcnt)
{
    const int tid = threadIdx.x;
    for (int i = blockIdx.x * 256 + tid; i < NBK * GSTR; i += 16 * 256) gcnt[i] = 0;
    if (blockIdx.x != 0) return;

    __shared__ __align__(16) unsigned short bl[10240];
    // W -> frag order, col-tiles 0..3
    for (int idx = tid; idx < 128 * 16; idx += 256) {
        const int f = idx >> 4, cq = idx & 15;
        const float4 w = *(const float4*)(W + f * 64 + cq * 4);
        const int kc = f >> 5, q = (f >> 3) & 3, j = f & 7;
        const float wf[4] = {w.x, w.y, w.z, w.w};
        #pragma unroll
        for (int i = 0; i < 4; ++i) {
            const int col = cq * 4 + i;
            bl[(col >> 4) * 2048 + kc * 512 + q * 128 + (col & 15) * 8 + j] = f2bf(wf[i]);
        }
    }
    // fold a_src/a_dst into col-tile 4
    for (int idx = tid; idx < 128 * 8; idx += 256) {
        const int f = idx >> 3, h = idx & 7;
        const float4 wa = *(const float4*)(W + f * 64 + h * 8);
        const float4 wb = *(const float4*)(W + f * 64 + h * 8 + 4);
        const float4 sa = *(const float4*)(a_src + h * 8);
        const float4 sb = *(const float4*)(a_src + h * 8 + 4);
        const float4 da = *(const float4*)(a_dst + h * 8);
        const float4 db = *(const float4*)(a_dst + h * 8 + 4);
        float esv = fmaf(wa.x, sa.x, fmaf(wa.y, sa.y, fmaf(wa.z, sa.z,
                    fmaf(wa.w, sa.w, fmaf(wb.x, sb.x, fmaf(wb.y, sb.y,
                    fmaf(wb.z, sb.z, wb.w * sb.w)))))));
        float edv = fmaf(wa.x, da.x, fmaf(wa.y, da.y, fmaf(wa.z, da.z,
                    fmaf(wa.w, da.w, fmaf(wb.x, db.x, fmaf(wb.y, db.y,
                    fmaf(wb.z, db.z, wb.w * db.w)))))));
        const int kc = f >> 5, q = (f >> 3) & 3, j = f & 7;
        bl[4 * 2048 + kc * 512 + q * 128 + h * 8 + j]       = f2bf(esv);
        bl[4 * 2048 + kc * 512 + q * 128 + (8 + h) * 8 + j] = f2bf(edv);
    }
    __syncthreads();
    for (int idx = tid; idx < 1280; idx += 256)
        ((uint4*)Bg)[idx] = ((const uint4*)bl)[idx];
}

// ---------------------------------------------------------------------------
// K1 (fused, 512 threads): blocks [0,NBPJ) = MFMA projection; blocks
// [NBPJ,NBPJ+NPB) = edge partition. Round 15: NPB 160->400 (part tail was
// running at ~5 waves/CU after proj drained — the 50us was the tail, not
// proj); gcnt padded to 64B/bucket to kill per-line atomic serialization.
// ---------------------------------------------------------------------------
__global__ __launch_bounds__(512) void fused_pp_kernel(
    const float* __restrict__ vert, const unsigned short* __restrict__ Bg,
    __hip_bfloat16* __restrict__ gb, float* __restrict__ es, float* __restrict__ ed,
    const int* __restrict__ edge, int* __restrict__ gcnt,
    unsigned int* __restrict__ packed)
{
    __shared__ __align__(16) char smem[28672];   // 28 KB
    const int tid = threadIdx.x;

    if (blockIdx.x < NBPJ) {
        // =================== proj branch ===================
        unsigned short* b_lds = (unsigned short*)smem;   // [0, 20480)
        const int nbeg = blockIdx.x * 128;
        const int lane = tid & 63, wv = tid >> 6;        // wv = M-tile 0..7
        const int mn   = lane & 15, quad = lane >> 4;

        // stage B: linear 20 KB copy (coalesced reads, conflict-free writes)
        for (int idx = tid; idx < 1280; idx += 512)
            *(uint4*)(smem + idx * 16) = ((const uint4*)Bg)[idx];

        // A fragments straight from global (32B/lane, coalesced)
        const int row = nbeg + wv * 16 + mn;
        bf16x8 afr[4];
        #pragma unroll
        for (int kc = 0; kc < 4; ++kc) {
            float4 p = make_float4(0.f, 0.f, 0.f, 0.f);
            float4 q4 = make_float4(0.f, 0.f, 0.f, 0.f);
            if (row < N_NODES) {
                const float* rp = vert + (size_t)row * IN_F + kc * 32 + quad * 8;
                p  = *(const float4*)rp;
                q4 = *(const float4*)(rp + 4);
            }
            bf16x8 a;
            a[0] = (short)f2bf(p.x);  a[1] = (short)f2bf(p.y);
            a[2] = (short)f2bf(p.z);  a[3] = (short)f2bf(p.w);
            a[4] = (short)f2bf(q4.x); a[5] = (short)f2bf(q4.y);
            a[6] = (short)f2bf(q4.z); a[7] = (short)f2bf(q4.w);
            afr[kc] = a;
        }
        __syncthreads();

        const unsigned short* bbase = b_lds + quad * 128 + mn * 8;
        f32x4 acc[5];
        #pragma unroll
        for (int c = 0; c < 5; ++c) acc[c] = (f32x4){0.f, 0.f, 0.f, 0.f};
        #pragma unroll
        for (int kc = 0; kc < 4; ++kc) {
            #pragma unroll
            for (int c = 0; c < 5; ++c) {
                const bf16x8 bfr = *(const bf16x8*)(bbase + c * 2048 + kc * 512);
                acc[c] = __builtin_amdgcn_mfma_f32_16x16x32_bf16(afr[kc], bfr, acc[c], 0, 0, 0);
            }
        }
        __syncthreads();

        // epilogue via LDS (padded layouts)
        unsigned short* gl = (unsigned short*)smem + wv * 1152;   // 16 x 72 shorts
        float* lesd = (float*)(smem + 18432) + wv * 320;          // 2 x 16 x 10 floats
        #pragma unroll
        for (int c = 0; c < 4; ++c)
            #pragma unroll
            for (int r = 0; r < 4; ++r)
                gl[(quad * 4 + r) * 72 + c * 16 + mn] = f2bf(acc[c][r]);
        {
            float* dst = (mn < 8) ? (lesd + mn) : (lesd + 160 + (mn - 8));
            #pragma unroll
            for (int r = 0; r < 4; ++r) dst[(quad * 4 + r) * 10] = acc[4][r];
        }
        __syncthreads();
        {   // g store: 16 rows x 128B per wave
            const int row2 = lane >> 2, part = lane & 3;
            const int node = nbeg + wv * 16 + row2;
            if (node < N_NODES) {
                const uint4* sp = (const uint4*)(gl + row2 * 72 + part * 16);
                *(uint4*)((unsigned short*)gb + (size_t)node * HID + part * 16) = sp[0];
                *(uint4*)((unsigned short*)gb + (size_t)node * HID + part * 16 + 8) = sp[1];
            }
        }
        {   // es/ed store
            const int nl = lane >> 2, h2 = (lane & 3) * 2;
            const int node = nbeg + wv * 16 + nl;
            if (node < N_NODES) {
                *(float2*)(es + node * NH + h2) = *(const float2*)(lesd + nl * 10 + h2);
                *(float2*)(ed + node * NH + h2) = *(const float2*)(lesd + 160 + nl * 10 + h2);
            }
        }
    } else {
        // =================== part branch (8 waves) ===================
        int* lh    = (int*)smem;               // 12500 B
        int* lbase = (int*)(smem + 12544);     // 12500 B
        const int pb = blockIdx.x - NBPJ;

        for (int i = tid; i < NBK; i += 512) lh[i] = 0;
        __syncthreads();
        const int4* src4 = (const int4*)(edge + pb * EPB);
        const int4* dst4 = (const int4*)(edge + N_EDGES + pb * EPB);
        for (int t = tid; t < EPB / 4; t += 512) {
            const int4 d = dst4[t];
            atomicAdd(&lh[d.x >> BSH], 1);
            atomicAdd(&lh[d.y >> BSH], 1);
            atomicAdd(&lh[d.z >> BSH], 1);
            atomicAdd(&lh[d.w >> BSH], 1);
        }
        __syncthreads();
        for (int i = tid; i < NBK; i += 512) {
            const int c = lh[i];
            lbase[i] = c ? (i * BCAPG + atomicAdd(&gcnt[i * GSTR], c)) : 0;
            lh[i] = 0;                       // reuse as local cursor
        }
        __syncthreads();
        for (int t = tid; t < EPB / 4; t += 512) {
            const int4 s = src4[t];
            const int4 d = dst4[t];
            int bk, pos;
            bk = d.x >> BSH; pos = min(lbase[bk] + atomicAdd(&lh[bk], 1), NBK * BCAPG - 1);
            packed[pos] = ((unsigned)s.x << BSH) | (d.x & (BSZ - 1));
            bk = d.y >> BSH; pos = min(lbase[bk] + atomicAdd(&lh[bk], 1), NBK * BCAPG - 1);
            packed[pos] = ((unsigned)s.y << BSH) | (d.y & (BSZ - 1));
            bk = d.z >> BSH; pos = min(lbase[bk] + atomicAdd(&lh[bk], 1), NBK * BCAPG - 1);
            packed[pos] = ((unsigned)s.z << BSH) | (d.z & (BSZ - 1));
            bk = d.w >> BSH; pos = min(lbase[bk] + atomicAdd(&lh[bk], 1), NBK * BCAPG - 1);
            packed[pos] = ((unsigned)s.w << BSH) | (d.w & (BSZ - 1));
        }
    }
}

// ---------------------------------------------------------------------------
// K5: per-bucket LDS CSR + two-phase softmax aggregation (unchanged round 14
// structure: pre-scaled ssrt, bulk/tail split, base+imm LDS broadcasts).
// ---------------------------------------------------------------------------
__global__ __launch_bounds__(256) void p2agg_kernel(
    const int* __restrict__ gcnt, const unsigned int* __restrict__ packed,
    const unsigned short* __restrict__ gb, const float* __restrict__ es,
    const float* __restrict__ ed, float* __restrict__ out)
{
    __shared__ unsigned int ssrt[BCAP];                       // 3328 B
    __shared__ __align__(16) unsigned short pexp[BCAP * 8];   // 13312 B fp16
    __shared__ int ldeg[BSZ], loffs[BSZ];
    __shared__ __align__(16) float led[BSZ * NH];             // 1 KB (tot 17.9 KB)
    unsigned int* epk = (unsigned int*)pexp;   // overlay: dead before pexp written

    const int tid  = threadIdx.x;
    const int b    = blockIdx.x;
    const int nbeg = b << BSH;
    const int ebase = b * BCAPG;
    const int ecnt  = min(gcnt[b * GSTR], BCAP);   // defensive clamp

    if (tid < BSZ) ldeg[tid] = 0;
    for (int i = tid; i < BSZ * NH; i += 256) led[i] = ed[nbeg * NH + i];
    __syncthreads();

    for (int i = tid; i < ecnt; i += 256) {
        const unsigned int p = packed[ebase + i];
        epk[i] = p;
        atomicAdd(&ldeg[p & (BSZ - 1)], 1);
    }
    __syncthreads();

    if (tid < BSZ) {
        int v = ldeg[tid];
        #pragma unroll
        for (int off = 1; off < BSZ; off <<= 1) {
            const int t = __shfl_up(v, off, 64);
            if (tid >= off) v += t;
        }
        loffs[tid] = v - ldeg[tid];   // exclusive
    }
    __syncthreads();

    for (int i = tid; i < ecnt; i += 256) {
        const unsigned int p = epk[i];
        const int pos = atomicAdd(&loffs[p & (BSZ - 1)], 1);
        ssrt[pos] = ((p >> BSH) << 7) | (p & (BSZ - 1));   // src*128 | dl
    }
    __syncthreads();

    // ---- phase A: batched score computation -> fp16 pexp ----
    for (int i = tid; i < ecnt; i += 256) {
        const unsigned pw = ssrt[i];
        const int src = (int)(pw >> 7), dl = (int)(pw & (BSZ - 1));
        const float4 e0 = *(const float4*)(es + (size_t)src * NH);
        const float4 e1 = *(const float4*)(es + (size_t)src * NH + 4);
        const float4 l0 = *(const float4*)(led + dl * NH);
        const float4 l1 = *(const float4*)(led + dl * NH + 4);
        float s[8] = {e0.x + l0.x, e0.y + l0.y, e0.z + l0.z, e0.w + l0.w,
                      e1.x + l1.x, e1.y + l1.y, e1.z + l1.z, e1.w + l1.w};
        #pragma unroll
        for (int k = 0; k < 8; ++k)
            s[k] = __expf(fmaxf(s[k], s[k] * NEG_SLOPE));
        __half2 h01 = __floats2half2_rn(s[0], s[1]);
        __half2 h23 = __floats2half2_rn(s[2], s[3]);
        __half2 h45 = __floats2half2_rn(s[4], s[5]);
        __half2 h67 = __floats2half2_rn(s[6], s[7]);
        uint4 w;
        w.x = *(unsigned*)&h01; w.y = *(unsigned*)&h23;
        w.z = *(unsigned*)&h45; w.w = *(unsigned*)&h67;
        *(uint4*)(pexp + i * 8) = w;
    }
    __syncthreads();

    // ---- phase B: aggregation ----
    const int lane  = tid & 63;
    const int wv    = tid >> 6;
    const int c2    = lane & 31;         // column-pair index (cols 2*c2, 2*c2+1)
    const int khalf = lane >> 5;         // 0: even edges, 1: odd edges
    const int h     = c2 >> 2;           // head of this column pair
    const unsigned c2_4 = (unsigned)(c2 << 2);
    const char* gbase = (const char*)gb;

#define BULK_STEP(s, pw)                                                      \
    {                                                                         \
        const float pe = __half2float(                                        \
            *(const __half*)(pexp + ((i + 2 * (s) + khalf) << 3) + h));       \
        const unsigned voff = ((pw) & ~127u) | c2_4;                          \
        const unsigned gu = *(const unsigned*)(gbase + voff);                 \
        acc0 = fmaf(pe, __uint_as_float(gu << 16), acc0);                     \
        acc1 = fmaf(pe, __uint_as_float(gu & 0xFFFF0000u), acc1);             \
        l += pe;                                                              \
    }

    for (int n = wv; n < BSZ; n += 4) {          // 100000 % 32 == 0: no guard
        const int end = loffs[n];                // post-scatter: segment end
        const int beg = end - ldeg[n];
        float l = 0.f, acc0 = 0.f, acc1 = 0.f;
        int i = beg;
        for (; i + 8 <= end; i += 8) {           // bulk: no clamp, no mask
            const unsigned pw0 = ssrt[i + khalf];
            const unsigned pw1 = ssrt[i + 2 + khalf];
            const unsigned pw2 = ssrt[i + 4 + khalf];
            const unsigned pw3 = ssrt[i + 6 + khalf];
            BULK_STEP(0, pw0); BULK_STEP(1, pw1);
            BULK_STEP(2, pw2); BULK_STEP(3, pw3);
        }
        if (i < end) {                           // masked tail (<8 edges)
            #pragma unroll
            for (int s = 0; s < 4; ++s) {
                const int e  = i + 2 * s + khalf;
                const int ec = min(e, end - 1);
                const unsigned pw = ssrt[ec];
                float pe = __half2float(*(const __half*)(pexp + (ec << 3) + h));
                pe = (e < end) ? pe : 0.f;
                const unsigned voff = (pw & ~127u) | c2_4;
                const unsigned gu = *(const unsigned*)(gbase + voff);
                acc0 = fmaf(pe, __uint_as_float(gu << 16), acc0);
                acc1 = fmaf(pe, __uint_as_float(gu & 0xFFFF0000u), acc1);
                l += pe;
            }
        }
        // combine even/odd halves (each lane then holds full sums)
        l    += __shfl_xor(l, 32);
        acc0 += __shfl_xor(acc0, 32);
        acc1 += __shfl_xor(acc1, 32);
        const float rl = 1.f / fmaxf(l, 1e-16f);
        float o0 = acc0 * rl, o1 = acc1 * rl;
        o0 = (o0 > 0.f) ? o0 : (__expf(o0) - 1.f);   // ELU (abs-err safe)
        o1 = (o1 > 0.f) ? o1 : (__expf(o1) - 1.f);
        const float ov = khalf ? o1 : o0;
        out[(size_t)(nbeg + n) * HID + c2 * 2 + khalf] = ov;
    }
#undef BULK_STEP
}

// ---------------------------------------------------------------------------
extern "C" void kernel_launch(void* const* d_in, const int* in_sizes, int n_in,
                              void* d_out, int out_size, void* d_ws, size_t ws_size,
                              hipStream_t stream)
{
    const float* vert  = (const float*)d_in[0];
    const int*   edge  = (const int*)  d_in[1];
    const float* W     = (const float*)d_in[2];
    const float* a_src = (const float*)d_in[3];
    const float* a_dst = (const float*)d_in[4];
    float* out = (float*)d_out;

    char* ws = (char*)d_ws;
    __hip_bfloat16* gb     = (__hip_bfloat16*)(ws);         // 12,800,000 B
    float*          es     = (float*)(ws + 12800000);       //  3,200,000 B
    float*          ed     = (float*)(ws + 16000000);       //  3,200,000 B
    unsigned int*   packed = (unsigned int*)(ws + 19200000);//  8,800,000 B (NBK*BCAPG*4)
    int*            gcnt   = (int*)(ws + 28000000);         //    200,000 B (padded 64B/bucket)
    unsigned short* Bg     = (unsigned short*)(ws + 28200000); // 20,480 B (28.22 MB tot)

    prep_kernel<<<16, 256, 0, stream>>>(W, a_src, a_dst, Bg, gcnt);
    fused_pp_kernel<<<NBPJ + NPB, 512, 0, stream>>>(
        vert, Bg, gb, es, ed, edge, gcnt, packed);
    p2agg_kernel<<<NBK, 256, 0, stream>>>(gcnt, packed, (const unsigned short*)gb, es, ed, out);
}

// Round 8
// 177.191 us; speedup vs baseline: 1.1645x; 1.1645x over previous
//
#include <hip/hip_runtime.h>
#include <hip/hip_bf16.h>
#include <hip/hip_fp16.h>
#include <math.h>

#define N_NODES 100000
#define N_EDGES 1600000
#define IN_F    128
#define NH      8
#define HD      8
#define HID     64   // NH*HD
#define NEG_SLOPE 0.2f

#define BSH   5      // fine bucket shift: 32 dst nodes per bucket
#define BSZ   32
#define NBK   3125   // 100000/32 exact (fine buckets)
#define NCB   196    // coarse buckets: ceil(100000/512)
#define CSTR  9216   // coarse bucket stride (mean 8163, +11 sigma)
#define BCAP  832    // LDS edge cap in p2agg (fine bucket, mean 512)
#define NBPJ  782    // proj blocks: ceil(100000/128), 128 nodes/block
#define NPB   160    // partition (pass A) blocks
#define EPB   10000  // edges per partition block (160*10000 = 1.6M exact)
#define GSTR  16     // gcnt stride: one 64B line per coarse bucket

typedef short bf16x8 __attribute__((ext_vector_type(8)));
typedef float f32x4  __attribute__((ext_vector_type(4)));

static __device__ __forceinline__ unsigned short f2bf(float x) {
    __hip_bfloat16 h = __float2bfloat16(x);
    return *(unsigned short*)&h;
}

// ---------------------------------------------------------------------------
// K0 prep: zero gcnt (196 padded lines) + build the 20 KB frag-order B-image.
// ---------------------------------------------------------------------------
__global__ __launch_bounds__(256) void prep_kernel(
    const float* __restrict__ W, const float* __restrict__ a_src,
    const float* __restrict__ a_dst, unsigned short* __restrict__ Bg,
    int* __restrict__ gcnt)
{
    const int tid = threadIdx.x;
    for (int i = blockIdx.x * 256 + tid; i < NCB * GSTR; i += 16 * 256) gcnt[i] = 0;
    if (blockIdx.x != 0) return;

    __shared__ __align__(16) unsigned short bl[10240];
    for (int idx = tid; idx < 128 * 16; idx += 256) {
        const int f = idx >> 4, cq = idx & 15;
        const float4 w = *(const float4*)(W + f * 64 + cq * 4);
        const int kc = f >> 5, q = (f >> 3) & 3, j = f & 7;
        const float wf[4] = {w.x, w.y, w.z, w.w};
        #pragma unroll
        for (int i = 0; i < 4; ++i) {
            const int col = cq * 4 + i;
            bl[(col >> 4) * 2048 + kc * 512 + q * 128 + (col & 15) * 8 + j] = f2bf(wf[i]);
        }
    }
    for (int idx = tid; idx < 128 * 8; idx += 256) {
        const int f = idx >> 3, h = idx & 7;
        const float4 wa = *(const float4*)(W + f * 64 + h * 8);
        const float4 wb = *(const float4*)(W + f * 64 + h * 8 + 4);
        const float4 sa = *(const float4*)(a_src + h * 8);
        const float4 sb = *(const float4*)(a_src + h * 8 + 4);
        const float4 da = *(const float4*)(a_dst + h * 8);
        const float4 db = *(const float4*)(a_dst + h * 8 + 4);
        float esv = fmaf(wa.x, sa.x, fmaf(wa.y, sa.y, fmaf(wa.z, sa.z,
                    fmaf(wa.w, sa.w, fmaf(wb.x, sb.x, fmaf(wb.y, sb.y,
                    fmaf(wb.z, sb.z, wb.w * sb.w)))))));
        float edv = fmaf(wa.x, da.x, fmaf(wa.y, da.y, fmaf(wa.z, da.z,
                    fmaf(wa.w, da.w, fmaf(wb.x, db.x, fmaf(wb.y, db.y,
                    fmaf(wb.z, db.z, wb.w * db.w)))))));
        const int kc = f >> 5, q = (f >> 3) & 3, j = f & 7;
        bl[4 * 2048 + kc * 512 + q * 128 + h * 8 + j]       = f2bf(esv);
        bl[4 * 2048 + kc * 512 + q * 128 + (8 + h) * 8 + j] = f2bf(edv);
    }
    __syncthreads();
    for (int idx = tid; idx < 1280; idx += 256)
        ((uint4*)Bg)[idx] = ((const uint4*)bl)[idx];
}

// ---------------------------------------------------------------------------
// K1 (fused, 512 threads): blocks [0,NBPJ) = MFMA projection (unchanged,
// round-6-proven); blocks [NBPJ,NBPJ+NPB) = radix pass A: 196 COARSE
// buckets (dst>>9). Runs lengthen ~3.2 -> ~51 edges (~204B), killing the
// cross-XCD partial-line write amplification (round 7: WRITE 60->77MB as
// runs shortened; this goes the other way). Value pack: (src<<9)|(dst&511).
// ---------------------------------------------------------------------------
__global__ __launch_bounds__(512) void fused_pp_kernel(
    const float* __restrict__ vert, const unsigned short* __restrict__ Bg,
    __hip_bfloat16* __restrict__ gb, float* __restrict__ es, float* __restrict__ ed,
    const int* __restrict__ edge, int* __restrict__ gcnt,
    unsigned int* __restrict__ packed)
{
    __shared__ __align__(16) char smem[28672];   // 28 KB
    const int tid = threadIdx.x;

    if (blockIdx.x < NBPJ) {
        // =================== proj branch (unchanged) ===================
        unsigned short* b_lds = (unsigned short*)smem;   // [0, 20480)
        const int nbeg = blockIdx.x * 128;
        const int lane = tid & 63, wv = tid >> 6;
        const int mn   = lane & 15, quad = lane >> 4;

        for (int idx = tid; idx < 1280; idx += 512)
            *(uint4*)(smem + idx * 16) = ((const uint4*)Bg)[idx];

        const int row = nbeg + wv * 16 + mn;
        bf16x8 afr[4];
        #pragma unroll
        for (int kc = 0; kc < 4; ++kc) {
            float4 p = make_float4(0.f, 0.f, 0.f, 0.f);
            float4 q4 = make_float4(0.f, 0.f, 0.f, 0.f);
            if (row < N_NODES) {
                const float* rp = vert + (size_t)row * IN_F + kc * 32 + quad * 8;
                p  = *(const float4*)rp;
                q4 = *(const float4*)(rp + 4);
            }
            bf16x8 a;
            a[0] = (short)f2bf(p.x);  a[1] = (short)f2bf(p.y);
            a[2] = (short)f2bf(p.z);  a[3] = (short)f2bf(p.w);
            a[4] = (short)f2bf(q4.x); a[5] = (short)f2bf(q4.y);
            a[6] = (short)f2bf(q4.z); a[7] = (short)f2bf(q4.w);
            afr[kc] = a;
        }
        __syncthreads();

        const unsigned short* bbase = b_lds + quad * 128 + mn * 8;
        f32x4 acc[5];
        #pragma unroll
        for (int c = 0; c < 5; ++c) acc[c] = (f32x4){0.f, 0.f, 0.f, 0.f};
        #pragma unroll
        for (int kc = 0; kc < 4; ++kc) {
            #pragma unroll
            for (int c = 0; c < 5; ++c) {
                const bf16x8 bfr = *(const bf16x8*)(bbase + c * 2048 + kc * 512);
                acc[c] = __builtin_amdgcn_mfma_f32_16x16x32_bf16(afr[kc], bfr, acc[c], 0, 0, 0);
            }
        }
        __syncthreads();

        unsigned short* gl = (unsigned short*)smem + wv * 1152;   // 16 x 72 shorts
        float* lesd = (float*)(smem + 18432) + wv * 320;          // 2 x 16 x 10 floats
        #pragma unroll
        for (int c = 0; c < 4; ++c)
            #pragma unroll
            for (int r = 0; r < 4; ++r)
                gl[(quad * 4 + r) * 72 + c * 16 + mn] = f2bf(acc[c][r]);
        {
            float* dst = (mn < 8) ? (lesd + mn) : (lesd + 160 + (mn - 8));
            #pragma unroll
            for (int r = 0; r < 4; ++r) dst[(quad * 4 + r) * 10] = acc[4][r];
        }
        __syncthreads();
        {
            const int row2 = lane >> 2, part = lane & 3;
            const int node = nbeg + wv * 16 + row2;
            if (node < N_NODES) {
                const uint4* sp = (const uint4*)(gl + row2 * 72 + part * 16);
                *(uint4*)((unsigned short*)gb + (size_t)node * HID + part * 16) = sp[0];
                *(uint4*)((unsigned short*)gb + (size_t)node * HID + part * 16 + 8) = sp[1];
            }
        }
        {
            const int nl = lane >> 2, h2 = (lane & 3) * 2;
            const int node = nbeg + wv * 16 + nl;
            if (node < N_NODES) {
                *(float2*)(es + node * NH + h2) = *(const float2*)(lesd + nl * 10 + h2);
                *(float2*)(ed + node * NH + h2) = *(const float2*)(lesd + 160 + nl * 10 + h2);
            }
        }
    } else {
        // =================== radix pass A (coarse, 196 buckets) ===========
        int* lh    = (int*)smem;                // 784 B
        int* lbase = (int*)(smem + 1024);       // 784 B
        const int pb = blockIdx.x - NBPJ;

        if (tid < NCB) lh[tid] = 0;
        __syncthreads();
        const int4* src4 = (const int4*)(edge + pb * EPB);
        const int4* dst4 = (const int4*)(edge + N_EDGES + pb * EPB);
        for (int t = tid; t < EPB / 4; t += 512) {
            const int4 d = dst4[t];
            atomicAdd(&lh[d.x >> 9], 1);
            atomicAdd(&lh[d.y >> 9], 1);
            atomicAdd(&lh[d.z >> 9], 1);
            atomicAdd(&lh[d.w >> 9], 1);
        }
        __syncthreads();
        if (tid < NCB) {
            const int c = lh[tid];
            lbase[tid] = c ? (tid * CSTR + atomicAdd(&gcnt[tid * GSTR], c)) : 0;
            lh[tid] = 0;                        // reuse as local cursor
        }
        __syncthreads();
        for (int t = tid; t < EPB / 4; t += 512) {
            const int4 s = src4[t];
            const int4 d = dst4[t];
            int bk, pos;
            bk = d.x >> 9; pos = min(lbase[bk] + atomicAdd(&lh[bk], 1), NCB * CSTR - 1);
            packed[pos] = ((unsigned)s.x << 9) | (unsigned)(d.x & 511);
            bk = d.y >> 9; pos = min(lbase[bk] + atomicAdd(&lh[bk], 1), NCB * CSTR - 1);
            packed[pos] = ((unsigned)s.y << 9) | (unsigned)(d.y & 511);
            bk = d.z >> 9; pos = min(lbase[bk] + atomicAdd(&lh[bk], 1), NCB * CSTR - 1);
            packed[pos] = ((unsigned)s.z << 9) | (unsigned)(d.z & 511);
            bk = d.w >> 9; pos = min(lbase[bk] + atomicAdd(&lh[bk], 1), NCB * CSTR - 1);
            packed[pos] = ((unsigned)s.w << 9) | (unsigned)(d.w & 511);
        }
    }
}

// ---------------------------------------------------------------------------
// K2 radix pass B: one coarse bucket per block. Contiguous read -> LDS,
// 16-way fine split in LDS, IN-PLACE sequential write-back, finfo emit.
// Values rewritten to p2agg's final (src<<7)|dl format. Zero global atomics.
// ---------------------------------------------------------------------------
__global__ __launch_bounds__(512) void radixb_kernel(
    const int* __restrict__ gcnt, unsigned int* __restrict__ packed,
    int2* __restrict__ finfo)
{
    __shared__ unsigned int ebuf[CSTR];    // 36,864 B
    __shared__ unsigned int stage[CSTR];   // 36,864 B
    __shared__ int fh[16], fpre[16];
    const int tid = threadIdx.x;
    const int cb  = blockIdx.x;
    const int cnt = min(gcnt[cb * GSTR], CSTR);
    unsigned int* in = packed + (size_t)cb * CSTR;

    if (tid < 16) fh[tid] = 0;
    __syncthreads();
    for (int i = tid; i < cnt; i += 512) {
        const unsigned v = in[i];
        ebuf[i] = v;
        atomicAdd(&fh[(v >> 5) & 15], 1);
    }
    __syncthreads();
    if (tid == 0) {
        int s = 0;
        #pragma unroll
        for (int f = 0; f < 16; ++f) { fpre[f] = s; s += fh[f]; }
    }
    __syncthreads();
    if (tid < 16) fh[tid] = fpre[tid];      // cursors
    __syncthreads();
    for (int i = tid; i < cnt; i += 512) {
        const unsigned v = ebuf[i];
        const int pos = atomicAdd(&fh[(v >> 5) & 15], 1);
        stage[pos] = ((v >> 9) << 7) | (v & 31);   // (src<<7)|dl
    }
    __syncthreads();
    for (int i = tid; i < cnt; i += 512) in[i] = stage[i];
    if (tid < 16) {
        const int fg = cb * 16 + tid;
        if (fg < NBK)
            finfo[fg] = make_int2(cb * CSTR + fpre[tid], fh[tid] - fpre[tid]);
    }
}

// ---------------------------------------------------------------------------
// K5: per-bucket LDS CSR + two-phase softmax aggregation. Round-6-proven
// inner structure; interface change only: (base,cnt) from finfo, packed
// values arrive pre-formatted as (src<<7)|dl (repack dropped).
// ---------------------------------------------------------------------------
__global__ __launch_bounds__(256) void p2agg_kernel(
    const int2* __restrict__ finfo, const unsigned int* __restrict__ packed,
    const unsigned short* __restrict__ gb, const float* __restrict__ es,
    const float* __restrict__ ed, float* __restrict__ out)
{
    __shared__ unsigned int ssrt[BCAP];                       // 3328 B
    __shared__ __align__(16) unsigned short pexp[BCAP * 8];   // 13312 B fp16
    __shared__ int ldeg[BSZ], loffs[BSZ];
    __shared__ __align__(16) float led[BSZ * NH];             // 1 KB
    unsigned int* epk = (unsigned int*)pexp;   // overlay: dead before pexp written

    const int tid  = threadIdx.x;
    const int b    = blockIdx.x;
    const int nbeg = b << BSH;
    const int2 fi  = finfo[b];
    const int ebase = fi.x;
    const int ecnt  = min(fi.y, BCAP);      // defensive clamp

    if (tid < BSZ) ldeg[tid] = 0;
    for (int i = tid; i < BSZ * NH; i += 256) led[i] = ed[nbeg * NH + i];
    __syncthreads();

    for (int i = tid; i < ecnt; i += 256) {
        const unsigned int p = packed[ebase + i];
        epk[i] = p;
        atomicAdd(&ldeg[p & (BSZ - 1)], 1);
    }
    __syncthreads();

    if (tid < BSZ) {
        int v = ldeg[tid];
        #pragma unroll
        for (int off = 1; off < BSZ; off <<= 1) {
            const int t = __shfl_up(v, off, 64);
            if (tid >= off) v += t;
        }
        loffs[tid] = v - ldeg[tid];   // exclusive
    }
    __syncthreads();

    for (int i = tid; i < ecnt; i += 256) {
        const unsigned int p = epk[i];
        const int pos = atomicAdd(&loffs[p & (BSZ - 1)], 1);
        ssrt[pos] = p;                 // already (src<<7)|dl
    }
    __syncthreads();

    // ---- phase A: batched score computation -> fp16 pexp ----
    for (int i = tid; i < ecnt; i += 256) {
        const unsigned pw = ssrt[i];
        const int src = (int)(pw >> 7), dl = (int)(pw & (BSZ - 1));
        const float4 e0 = *(const float4*)(es + (size_t)src * NH);
        const float4 e1 = *(const float4*)(es + (size_t)src * NH + 4);
        const float4 l0 = *(const float4*)(led + dl * NH);
        const float4 l1 = *(const float4*)(led + dl * NH + 4);
        float s[8] = {e0.x + l0.x, e0.y + l0.y, e0.z + l0.z, e0.w + l0.w,
                      e1.x + l1.x, e1.y + l1.y, e1.z + l1.z, e1.w + l1.w};
        #pragma unroll
        for (int k = 0; k < 8; ++k)
            s[k] = __expf(fmaxf(s[k], s[k] * NEG_SLOPE));
        __half2 h01 = __floats2half2_rn(s[0], s[1]);
        __half2 h23 = __floats2half2_rn(s[2], s[3]);
        __half2 h45 = __floats2half2_rn(s[4], s[5]);
        __half2 h67 = __floats2half2_rn(s[6], s[7]);
        uint4 w;
        w.x = *(unsigned*)&h01; w.y = *(unsigned*)&h23;
        w.z = *(unsigned*)&h45; w.w = *(unsigned*)&h67;
        *(uint4*)(pexp + i * 8) = w;
    }
    __syncthreads();

    // ---- phase B: aggregation ----
    const int lane  = tid & 63;
    const int wv    = tid >> 6;
    const int c2    = lane & 31;
    const int khalf = lane >> 5;
    const int h     = c2 >> 2;
    const unsigned c2_4 = (unsigned)(c2 << 2);
    const char* gbase = (const char*)gb;

#define BULK_STEP(s, pw)                                                      \
    {                                                                         \
        const float pe = __half2float(                                        \
            *(const __half*)(pexp + ((i + 2 * (s) + khalf) << 3) + h));       \
        const unsigned voff = ((pw) & ~127u) | c2_4;                          \
        const unsigned gu = *(const unsigned*)(gbase + voff);                 \
        acc0 = fmaf(pe, __uint_as_float(gu << 16), acc0);                     \
        acc1 = fmaf(pe, __uint_as_float(gu & 0xFFFF0000u), acc1);             \
        l += pe;                                                              \
    }

    for (int n = wv; n < BSZ; n += 4) {
        const int end = loffs[n];
        const int beg = end - ldeg[n];
        float l = 0.f, acc0 = 0.f, acc1 = 0.f;
        int i = beg;
        for (; i + 8 <= end; i += 8) {
            const unsigned pw0 = ssrt[i + khalf];
            const unsigned pw1 = ssrt[i + 2 + khalf];
            const unsigned pw2 = ssrt[i + 4 + khalf];
            const unsigned pw3 = ssrt[i + 6 + khalf];
            BULK_STEP(0, pw0); BULK_STEP(1, pw1);
            BULK_STEP(2, pw2); BULK_STEP(3, pw3);
        }
        if (i < end) {
            #pragma unroll
            for (int s = 0; s < 4; ++s) {
                const int e  = i + 2 * s + khalf;
                const int ec = min(e, end - 1);
                const unsigned pw = ssrt[ec];
                float pe = __half2float(*(const __half*)(pexp + (ec << 3) + h));
                pe = (e < end) ? pe : 0.f;
                const unsigned voff = (pw & ~127u) | c2_4;
                const unsigned gu = *(const unsigned*)(gbase + voff);
                acc0 = fmaf(pe, __uint_as_float(gu << 16), acc0);
                acc1 = fmaf(pe, __uint_as_float(gu & 0xFFFF0000u), acc1);
                l += pe;
            }
        }
        l    += __shfl_xor(l, 32);
        acc0 += __shfl_xor(acc0, 32);
        acc1 += __shfl_xor(acc1, 32);
        const float rl = 1.f / fmaxf(l, 1e-16f);
        float o0 = acc0 * rl, o1 = acc1 * rl;
        o0 = (o0 > 0.f) ? o0 : (__expf(o0) - 1.f);   // ELU
        o1 = (o1 > 0.f) ? o1 : (__expf(o1) - 1.f);
        const float ov = khalf ? o1 : o0;
        out[(size_t)(nbeg + n) * HID + c2 * 2 + khalf] = ov;
    }
#undef BULK_STEP
}

// ---------------------------------------------------------------------------
extern "C" void kernel_launch(void* const* d_in, const int* in_sizes, int n_in,
                              void* d_out, int out_size, void* d_ws, size_t ws_size,
                              hipStream_t stream)
{
    const float* vert  = (const float*)d_in[0];
    const int*   edge  = (const int*)  d_in[1];
    const float* W     = (const float*)d_in[2];
    const float* a_src = (const float*)d_in[3];
    const float* a_dst = (const float*)d_in[4];
    float* out = (float*)d_out;

    char* ws = (char*)d_ws;
    __hip_bfloat16* gb     = (__hip_bfloat16*)(ws);            // 12,800,000 B
    float*          es     = (float*)(ws + 12800000);          //  3,200,000 B
    float*          ed     = (float*)(ws + 16000000);          //  3,200,000 B
    unsigned int*   packed = (unsigned int*)(ws + 19200000);   //  7,225,344 B (NCB*CSTR*4)
    int*            gcnt   = (int*)(ws + 26425344);            //     12,544 B
    int2*           finfo  = (int2*)(ws + 26437888);           //     25,000 B
    unsigned short* Bg     = (unsigned short*)(ws + 26462896); //     20,480 B (26.5 MB tot)

    prep_kernel<<<16, 256, 0, stream>>>(W, a_src, a_dst, Bg, gcnt);
    fused_pp_kernel<<<NBPJ + NPB, 512, 0, stream>>>(
        vert, Bg, gb, es, ed, edge, gcnt, packed);
    radixb_kernel<<<NCB, 512, 0, stream>>>(gcnt, packed, finfo);
    p2agg_kernel<<<NBK, 256, 0, stream>>>(finfo, packed, (const unsigned short*)gb, es, ed, out);
}